// Round 19
// baseline (415.582 us; speedup 1.0000x reference)
//
#include <hip/hip_runtime.h>

typedef unsigned short u16;
typedef unsigned int   u32;
typedef __attribute__((ext_vector_type(8))) short short8;   // 8 x bf16
typedef __attribute__((ext_vector_type(4))) float f32x4;

__device__ __forceinline__ float b2f(u16 u) {
  union { float f; u32 i; } v; v.i = ((u32)u) << 16; return v.f;
}
__device__ __forceinline__ u16 f2b(float f) {
  union { float f; u32 i; } v; v.f = f;
  u32 r = v.i + 0x7fffu + ((v.i >> 16) & 1u);   // RNE
  return (u16)(r >> 16);
}

__device__ __forceinline__ void gload_lds16(const void* g, void* l) {
  __builtin_amdgcn_global_load_lds(
      (const __attribute__((address_space(1))) void*)g,
      (__attribute__((address_space(3))) void*)l, 16, 0, 0);
}

template <int N> __device__ __forceinline__ void wait_vmcnt() {
  if constexpr (N == 0)      asm volatile("s_waitcnt vmcnt(0)" ::: "memory");
  else if constexpr (N == 2) asm volatile("s_waitcnt vmcnt(2)" ::: "memory");
  else if constexpr (N == 3) asm volatile("s_waitcnt vmcnt(3)" ::: "memory");
  else if constexpr (N == 4) asm volatile("s_waitcnt vmcnt(4)" ::: "memory");
  else if constexpr (N == 6) asm volatile("s_waitcnt vmcnt(6)" ::: "memory");
  else static_assert(N < 0, "unsupported vmcnt literal");
}

// ---------------- f32 -> bf16 converts ----------------
__device__ __forceinline__ ushort4 cvt4(float4 v) {
  ushort4 o;
  o.x = f2b(v.x); o.y = f2b(v.y); o.z = f2b(v.z); o.w = f2b(v.w);
  return o;
}

__global__ __launch_bounds__(256) void cvt_hp(const float* __restrict__ hs,
                                              const float* __restrict__ wp,
                                              u16* __restrict__ h_bf,
                                              u16* __restrict__ wp_bf) {
  const long H4 = 2097152, W4 = 12582912;   // float4 counts
  for (long i = (long)blockIdx.x * 256 + threadIdx.x; i < H4 + W4;
       i += (long)gridDim.x * 256) {
    if (i < H4)
      ((ushort4*)h_bf)[i] = cvt4(((const float4*)hs)[i]);
    else
      ((ushort4*)wp_bf)[i - H4] = cvt4(((const float4*)wp)[i - H4]);
  }
}

__device__ __forceinline__ short8 frag_ld64(const u16* base, int rbase, int kk,
                                            int fr, int fq) {
  const int r = rbase + fr;
  return *(const short8*)(base + r * 64 + ((((kk << 2) + fq) ^ (r & 7)) << 3));
}

// ============ GEMM1: tile 256x192, SINGLE-barrier double buffer =============
// All 7 staging loads (A x4 + B x3 for tile t+1) issue in phase 1 into buf^1;
// nothing writes the buffer being read -> the lgkm(0)+barrier is gone.
// Race proof: reads of buf(t&1) complete before the end-of-t barrier; writes
// into buf(t&1) occur only at t+1 (post-barrier); reads at t+1 are guarded by
// the pre-barrier vmcnt(0). Cover: loads issue ph1, waited ~2500-3000 cy later
// (>= 3x HBM latency) so the drain retires already-landed loads.
__global__ __launch_bounds__(512, 2) void gemm8p(const u16* __restrict__ A,
                                                 const u16* __restrict__ B,
                                                 u16* __restrict__ Cq,
                                                 u16* __restrict__ VT,
                                                 int M, int N, int K) {
  constexpr int AE = 16384;                 // A region u16 (256x64)
  constexpr int BUFSZ = AE + 12288;         // + B region (192x64) = 28672 u16
  __shared__ u16 lds[2 * BUFSZ];            // 114,688 B
  const int tid = threadIdx.x;
  const int wid = tid >> 6, lane = tid & 63;
  const int fr = lane & 15, fq = lane >> 4;
  const int mA = (wid >> 2) * 128;          // wm in {0,1}
  const int nB = (wid & 3) * 48;            // wn in {0..3}

  const int nty = M >> 8;                   // 8
  const int qx = gridDim.x >> 3;
  const int wg = (blockIdx.x & 7) * qx + (blockIdx.x >> 3);
  const int by = wg % nty, bx = wg / nty;
  const long row0 = (long)by * 256, col0 = (long)bx * 192;

  const int rr8 = tid >> 3;
  const int jl = (tid & 7) ^ (rr8 & 7);
  const u16* gA = A + (row0 + rr8) * (long)K + jl * 8;
  const u16* gB = B + (col0 + rr8) * (long)K + jl * 8;

  f32x4 acc[8][3];
#pragma unroll
  for (int m = 0; m < 8; ++m)
#pragma unroll
    for (int n = 0; n < 3; ++n) acc[m][n] = f32x4{0.f, 0.f, 0.f, 0.f};

  const int NT = K >> 6;                    // BK = 64

  auto stageA = [&](int i, int t) {
    gload_lds16(gA + (long)(i * 64) * K + (long)t * 64,
                lds + (t & 1) * BUFSZ + (i * 512 + tid) * 8);
  };
  auto stageB = [&](int i, int t) {
    gload_lds16(gB + (long)(i * 64) * K + (long)t * 64,
                lds + (t & 1) * BUFSZ + AE + (i * 512 + tid) * 8);
  };

  // prologue: tile 0 only (A+B, 7 loads)
#pragma unroll
  for (int i = 0; i < 4; ++i) stageA(i, 0);
#pragma unroll
  for (int i = 0; i < 3; ++i) stageB(i, 0);
  wait_vmcnt<0>();
  __builtin_amdgcn_s_barrier();

  for (int t = 0; t < NT; ++t) {
    const u16* SA = lds + (t & 1) * BUFSZ;
    const u16* SB = SA + AE;
    short8 a0[4], a1[4], b0[3], b1[3];

    // ---- phase 1: frags + ALL staging for t+1 (into buf^1); 12 MFMA ----
#pragma unroll
    for (int m = 0; m < 4; ++m) a0[m] = frag_ld64(SA, mA + m * 16, 0, fr, fq);
#pragma unroll
    for (int n = 0; n < 3; ++n) b0[n] = frag_ld64(SB, nB + n * 16, 0, fr, fq);
#pragma unroll
    for (int n = 0; n < 3; ++n) b1[n] = frag_ld64(SB, nB + n * 16, 1, fr, fq);
    if (t + 1 < NT) {
#pragma unroll
      for (int i = 0; i < 4; ++i) stageA(i, t + 1);
#pragma unroll
      for (int i = 0; i < 3; ++i) stageB(i, t + 1);
    }
    __builtin_amdgcn_s_setprio(1);
#pragma unroll
    for (int m = 0; m < 4; ++m)
#pragma unroll
      for (int n = 0; n < 3; ++n)
        acc[m][n] = __builtin_amdgcn_mfma_f32_16x16x32_bf16(a0[m], b0[n], acc[m][n], 0, 0, 0);
    __builtin_amdgcn_s_setprio(0);

    // ---- phases 2-4 (no barriers; active buffer is never written) ----
#pragma unroll
    for (int m = 0; m < 4; ++m) a1[m] = frag_ld64(SA, mA + 64 + m * 16, 0, fr, fq);
    __builtin_amdgcn_s_setprio(1);
#pragma unroll
    for (int m = 0; m < 4; ++m)
#pragma unroll
      for (int n = 0; n < 3; ++n)
        acc[4 + m][n] = __builtin_amdgcn_mfma_f32_16x16x32_bf16(a1[m], b0[n], acc[4 + m][n], 0, 0, 0);
    __builtin_amdgcn_s_setprio(0);

#pragma unroll
    for (int m = 0; m < 4; ++m) a0[m] = frag_ld64(SA, mA + m * 16, 1, fr, fq);
    __builtin_amdgcn_s_setprio(1);
#pragma unroll
    for (int m = 0; m < 4; ++m)
#pragma unroll
      for (int n = 0; n < 3; ++n)
        acc[m][n] = __builtin_amdgcn_mfma_f32_16x16x32_bf16(a0[m], b1[n], acc[m][n], 0, 0, 0);
    __builtin_amdgcn_s_setprio(0);

#pragma unroll
    for (int m = 0; m < 4; ++m) a1[m] = frag_ld64(SA, mA + 64 + m * 16, 1, fr, fq);
    __builtin_amdgcn_s_setprio(1);
#pragma unroll
    for (int m = 0; m < 4; ++m)
#pragma unroll
      for (int n = 0; n < 3; ++n)
        acc[4 + m][n] = __builtin_amdgcn_mfma_f32_16x16x32_bf16(a1[m], b1[n], acc[4 + m][n], 0, 0, 0);
    __builtin_amdgcn_s_setprio(0);
    wait_vmcnt<0>();                         // t+1 staged (issued ph1, covered)
    __builtin_amdgcn_s_barrier();            // single barrier per K-tile
  }

#pragma unroll
  for (int m = 0; m < 8; ++m)
#pragma unroll
    for (int n = 0; n < 3; ++n) {
      const long c = col0 + nB + n * 16 + fr;
      const long rb = row0 + mA + m * 16 + fq * 4;
      if (c >= 8192) {
        ushort4 o;
        o.x = f2b(acc[m][n][0]); o.y = f2b(acc[m][n][1]);
        o.z = f2b(acc[m][n][2]); o.w = f2b(acc[m][n][3]);
        *(ushort4*)(VT + (c - 8192) * 2048 + rb) = o;
      } else {
#pragma unroll
        for (int j = 0; j < 4; ++j) Cq[(rb + j) * N + c] = f2b(acc[m][n][j]);
      }
    }
}

// ============ GEMM2: tile 128x128, 2 blocks/CU, SINGLE-barrier ==============
__global__ __launch_bounds__(256, 2) void gemm2_128(const u16* __restrict__ A,
                                                    const u16* __restrict__ B,
                                                    float* __restrict__ C,
                                                    int M, int N, int K) {
  constexpr int AE = 8192;                  // A region u16 (128x64)
  constexpr int BUFSZ = 2 * AE;             // + B region = 16384 u16
  __shared__ u16 lds[2 * BUFSZ];            // 65,536 B
  const int tid = threadIdx.x;
  const int wid = tid >> 6, lane = tid & 63;
  const int fr = lane & 15, fq = lane >> 4;
  const int mA = (wid >> 1) * 64;
  const int nB = (wid & 1) * 64;

  const int nty = M >> 7;                   // 16
  const int qx = gridDim.x >> 3;
  const int wg = (blockIdx.x & 7) * qx + (blockIdx.x >> 3);
  const int by = wg % nty, bx = wg / nty;
  const long row0 = (long)by * 128, col0 = (long)bx * 128;

  const int rr8 = tid >> 3;                 // 0..31
  const int jl = (tid & 7) ^ (rr8 & 7);
  const u16* gA = A + (row0 + rr8) * (long)K + jl * 8;
  const u16* gB = B + (col0 + rr8) * (long)K + jl * 8;

  f32x4 acc[4][4];
#pragma unroll
  for (int m = 0; m < 4; ++m)
#pragma unroll
    for (int n = 0; n < 4; ++n) acc[m][n] = f32x4{0.f, 0.f, 0.f, 0.f};

  const int NT = K >> 6;

  auto stageA = [&](int i, int t) {
    gload_lds16(gA + (long)(i * 32) * K + (long)t * 64,
                lds + (t & 1) * BUFSZ + (i * 256 + tid) * 8);
  };
  auto stageB = [&](int i, int t) {
    gload_lds16(gB + (long)(i * 32) * K + (long)t * 64,
                lds + (t & 1) * BUFSZ + AE + (i * 256 + tid) * 8);
  };

  // prologue: tile 0 only (A+B, 8 loads)
#pragma unroll
  for (int i = 0; i < 4; ++i) stageA(i, 0);
#pragma unroll
  for (int i = 0; i < 4; ++i) stageB(i, 0);
  wait_vmcnt<0>();
  __builtin_amdgcn_s_barrier();

  for (int t = 0; t < NT; ++t) {
    const u16* SA = lds + (t & 1) * BUFSZ;
    const u16* SB = SA + AE;
    short8 a[2], b0[4], b1[4];

    // ---- phase 1: frags + ALL staging for t+1; 8 MFMA ----
    a[0] = frag_ld64(SA, mA +  0, 0, fr, fq);
    a[1] = frag_ld64(SA, mA + 16, 0, fr, fq);
#pragma unroll
    for (int n = 0; n < 4; ++n) b0[n] = frag_ld64(SB, nB + n * 16, 0, fr, fq);
#pragma unroll
    for (int n = 0; n < 4; ++n) b1[n] = frag_ld64(SB, nB + n * 16, 1, fr, fq);
    if (t + 1 < NT) {
#pragma unroll
      for (int i = 0; i < 4; ++i) stageA(i, t + 1);
#pragma unroll
      for (int i = 0; i < 4; ++i) stageB(i, t + 1);
    }
    __builtin_amdgcn_s_setprio(1);
#pragma unroll
    for (int m = 0; m < 2; ++m)
#pragma unroll
      for (int n = 0; n < 4; ++n)
        acc[m][n] = __builtin_amdgcn_mfma_f32_16x16x32_bf16(a[m], b0[n], acc[m][n], 0, 0, 0);
    __builtin_amdgcn_s_setprio(0);

    // ---- phases 2-4 (no barriers) ----
    a[0] = frag_ld64(SA, mA + 32, 0, fr, fq);
    a[1] = frag_ld64(SA, mA + 48, 0, fr, fq);
    __builtin_amdgcn_s_setprio(1);
#pragma unroll
    for (int m = 0; m < 2; ++m)
#pragma unroll
      for (int n = 0; n < 4; ++n)
        acc[2 + m][n] = __builtin_amdgcn_mfma_f32_16x16x32_bf16(a[m], b0[n], acc[2 + m][n], 0, 0, 0);
    __builtin_amdgcn_s_setprio(0);

    a[0] = frag_ld64(SA, mA +  0, 1, fr, fq);
    a[1] = frag_ld64(SA, mA + 16, 1, fr, fq);
    __builtin_amdgcn_s_setprio(1);
#pragma unroll
    for (int m = 0; m < 2; ++m)
#pragma unroll
      for (int n = 0; n < 4; ++n)
        acc[m][n] = __builtin_amdgcn_mfma_f32_16x16x32_bf16(a[m], b1[n], acc[m][n], 0, 0, 0);
    __builtin_amdgcn_s_setprio(0);

    a[0] = frag_ld64(SA, mA + 32, 1, fr, fq);
    a[1] = frag_ld64(SA, mA + 48, 1, fr, fq);
    __builtin_amdgcn_s_setprio(1);
#pragma unroll
    for (int m = 0; m < 2; ++m)
#pragma unroll
      for (int n = 0; n < 4; ++n)
        acc[2 + m][n] = __builtin_amdgcn_mfma_f32_16x16x32_bf16(a[m], b1[n], acc[2 + m][n], 0, 0, 0);
    __builtin_amdgcn_s_setprio(0);
    wait_vmcnt<0>();
    __builtin_amdgcn_s_barrier();            // single barrier per K-tile
  }

#pragma unroll
  for (int m = 0; m < 4; ++m)
#pragma unroll
    for (int n = 0; n < 4; ++n)
#pragma unroll
      for (int j = 0; j < 4; ++j) {
        const long r = row0 + mA + m * 16 + fq * 4 + j;
        const long c = col0 + nB + n * 16 + fr;
        C[r * N + c] = acc[m][n][j];
      }
}

// -------- RoPE on q,k (rope-only, R18-exact) --------------------------------
__global__ __launch_bounds__(256) void rope_qk(u16* __restrict__ qkv,
                                               const float* __restrict__ cosb,
                                               const float* __restrict__ sinb) {
  const int idx = blockIdx.x * 256 + threadIdx.x;   // grid exact: 2,097,152
  const int dq  = idx & 15;
  const int h   = (idx >> 4) & 31;
  const int seg = (idx >> 9) & 1;                   // 0 = q, 1 = k
  const int s   = idx >> 10;
  const int d0  = dq * 4;
  u16* base = qkv + (long)s * 12288 + seg * 4096 + h * 128;
  const ushort4 x1 = *(const ushort4*)(base + d0);
  const ushort4 x2 = *(const ushort4*)(base + d0 + 64);
  const float4 c1 = *(const float4*)(cosb + s * 128 + d0);
  const float4 s1 = *(const float4*)(sinb + s * 128 + d0);
  const float4 c2 = *(const float4*)(cosb + s * 128 + d0 + 64);
  const float4 s2 = *(const float4*)(sinb + s * 128 + d0 + 64);
  const float scale = seg ? 1.0f : 0.08838834764831845f;   // 1/sqrt(128) on q
  float x1f[4] = {b2f(x1.x), b2f(x1.y), b2f(x1.z), b2f(x1.w)};
  float x2f[4] = {b2f(x2.x), b2f(x2.y), b2f(x2.z), b2f(x2.w)};
  const float c1a[4] = {c1.x, c1.y, c1.z, c1.w}, s1a[4] = {s1.x, s1.y, s1.z, s1.w};
  const float c2a[4] = {c2.x, c2.y, c2.z, c2.w}, s2a[4] = {s2.x, s2.y, s2.z, s2.w};
  ushort4 o1, o2;
  u16* o1p = (u16*)&o1; u16* o2p = (u16*)&o2;
#pragma unroll
  for (int j = 0; j < 4; ++j) {
    o1p[j] = f2b((x1f[j] * c1a[j] - x2f[j] * s1a[j]) * scale);
    o2p[j] = f2b((x2f[j] * c2a[j] + x1f[j] * s2a[j]) * scale);
  }
  *(ushort4*)(base + d0) = o1;
  *(ushort4*)(base + d0 + 64) = o2;
}

// ------- causal flash attention (R18-exact) + wo-convert tail-fill ----------
__global__ __launch_bounds__(256, 2) void attn_fwd(const u16* __restrict__ Qb,
                                                   const u16* __restrict__ Kb,
                                                   const u16* __restrict__ Vt,
                                                   u16* __restrict__ Ob,
                                                   const float* __restrict__ wo,
                                                   u16* __restrict__ wo_bf) {
  if (blockIdx.x >= 512) {                   // wo convert tail-fill
    const int n4 = 4194304;
    for (long i = (long)(blockIdx.x - 512) * 256 + threadIdx.x; i < n4;
         i += (long)2048 * 256)
      ((ushort4*)wo_bf)[i] = cvt4(((const float4*)wo)[i]);
    return;
  }
  const int bid = blockIdx.x;                // 0..511
  const int half = bid >> 8, ii = bid & 255;
  const int h = (ii >> 4) | (half << 4);     // 0..31
  const int qt = half ? 15 - (ii & 15) : (ii & 15);
  const int q0 = qt * 128;
  const int nt = 2 * qt + 2;
  const int tid = threadIdx.x;
  const int wid = tid >> 6, lane = tid & 63;
  const int fr = lane & 15, fq = lane >> 4;

  __shared__ u16 Ks[2][64 * 128];    // 2 x 16 KB (double-buffered)
  __shared__ u16 Vts[128 * 64];      // 16 KB (single)
  __shared__ u16 Ps[4][32 * 64];     // 16 KB, XOR-swizzled pitch 64

  short8 ones;
#pragma unroll
  for (int i = 0; i < 8; ++i) ones[i] = (short)0x3F80;   // bf16 1.0

  auto stageK = [&](int t, int buf) {
    const int kv0 = t * 64;
#pragma unroll
    for (int i = 0; i < 4; ++i) {
      const int c = wid * 4 + i;
      const int r = c * 4 + (lane >> 4);
      const int p = lane & 15;
      const int jsrc = p ^ (r & 7);
      gload_lds16(Kb + (long)(kv0 + r) * 12288 + h * 128 + jsrc * 8,
                  (char*)Ks[buf] + c * 1024);
    }
  };
  auto stageV = [&](int t) {
    const int kv0 = t * 64;
#pragma unroll
    for (int i = 0; i < 4; ++i) {
      const int c = wid * 4 + i;
      const int d = c * 8 + (lane >> 3);
      const int p = lane & 7;
      const int jsrc = p ^ (d & 7);
      gload_lds16(Vt + (long)(h * 128 + d) * 2048 + kv0 + jsrc * 8,
                  (char*)Vts + c * 1024);
    }
  };

  const int wq_hi = q0 + wid * 32 + 31;   // wave's max q row

  short8 qf[2][4];
#pragma unroll
  for (int m = 0; m < 2; ++m) {
    const long qrow = q0 + wid * 32 + m * 16 + fr;
#pragma unroll
    for (int kk = 0; kk < 4; ++kk)
      qf[m][kk] = *(const short8*)(Qb + qrow * 12288 + h * 128 + kk * 32 + fq * 8);
  }

  f32x4 Oacc[2][8], Sacc[2];
#pragma unroll
  for (int m = 0; m < 2; ++m) {
#pragma unroll
    for (int f = 0; f < 8; ++f) Oacc[m][f] = f32x4{0.f, 0.f, 0.f, 0.f};
    Sacc[m] = f32x4{0.f, 0.f, 0.f, 0.f};
  }
  float mrun[2];
  mrun[0] = -1e30f; mrun[1] = -1e30f;

  stageK(0, 0);
  wait_vmcnt<0>();
  __builtin_amdgcn_s_barrier();

  for (int t = 0; t < nt; ++t) {
    const int cur = t & 1;
    const int kv0 = t * 64;
    stageV(t);                               // V(t): 4 loads (issued first)
    if (t + 1 < nt) stageK(t + 1, cur ^ 1);  // K(t+1): 4 loads behind V

    const bool skip = kv0 > wq_hi;           // wave-uniform causal skip
    float P[2][4][4];
    if (!skip) {
      // swapped QK^T: lane = q-column (q=fr); reg j = kv=kv0+16n+4fq+j
      f32x4 S[2][4];
#pragma unroll
      for (int m = 0; m < 2; ++m)
#pragma unroll
        for (int n = 0; n < 4; ++n) S[m][n] = f32x4{0.f, 0.f, 0.f, 0.f};
      __builtin_amdgcn_s_setprio(1);
#pragma unroll
      for (int kk = 0; kk < 4; ++kk) {
        short8 kf[4];
#pragma unroll
        for (int n = 0; n < 4; ++n) {
          const int r = n * 16 + fr;
          const int p = (kk * 4 + fq) ^ (r & 7);
          kf[n] = *(const short8*)((const char*)Ks[cur] + r * 256 + p * 16);
        }
#pragma unroll
        for (int m = 0; m < 2; ++m)
#pragma unroll
          for (int n = 0; n < 4; ++n)
            S[m][n] = __builtin_amdgcn_mfma_f32_16x16x32_bf16(kf[n], qf[m][kk], S[m][n], 0, 0, 0);
      }
      __builtin_amdgcn_s_setprio(0);

#pragma unroll
      for (int m = 0; m < 2; ++m) {
        const int qi = q0 + wid * 32 + m * 16 + fr;   // lane's q column
        float tm = -1e30f;
#pragma unroll
        for (int n = 0; n < 4; ++n)
#pragma unroll
          for (int j = 0; j < 4; ++j) {
            const int kv = kv0 + n * 16 + fq * 4 + j;
            const float s = (kv <= qi) ? S[m][n][j] : -1e30f;
            P[m][n][j] = s;
            tm = fmaxf(tm, s);
          }
        tm = fmaxf(tm, __shfl_xor(tm, 16));
        tm = fmaxf(tm, __shfl_xor(tm, 32));
        // defer-max (T13): rescale only when max grew beyond THR=8
        if (__any(tm > mrun[m] + 8.f)) {
          const float mn = fmaxf(mrun[m], tm);
          const float al = __expf(mrun[m] - mn);
          mrun[m] = mn;
          float alr[4];
#pragma unroll
          for (int j = 0; j < 4; ++j) alr[j] = __shfl(al, fq * 4 + j);
#pragma unroll
          for (int f = 0; f < 8; ++f) {
            f32x4 o = Oacc[m][f];
#pragma unroll
            for (int j = 0; j < 4; ++j) o[j] *= alr[j];
            Oacc[m][f] = o;
          }
#pragma unroll
          for (int j = 0; j < 4; ++j) Sacc[m][j] *= alr[j];
        }
#pragma unroll
        for (int n = 0; n < 4; ++n)
#pragma unroll
          for (int j = 0; j < 4; ++j)
            P[m][n][j] = __expf(P[m][n][j] - mrun[m]);
      }

      // Ps write: row q=16m+fr, byte col (32n+8fq) ^ ((fr&7)<<4)
#pragma unroll
      for (int m = 0; m < 2; ++m)
#pragma unroll
        for (int n = 0; n < 4; ++n) {
          ushort4 w;
          u16* wp_ = (u16*)&w;
#pragma unroll
          for (int j = 0; j < 4; ++j) wp_[j] = f2b(P[m][n][j]);
          const int off = (m * 16 + fr) * 128 + ((n * 32 + fq * 8) ^ ((fr & 7) << 4));
          *(ushort4*)((char*)Ps[wid] + off) = w;
        }
    }

    // V(t) landed (4 oldest); K(t+1) stays in flight (counted, T4)
    if (t + 1 < nt) wait_vmcnt<4>();
    else            wait_vmcnt<0>();
    __builtin_amdgcn_s_barrier();

    if (!skip) {
      __builtin_amdgcn_s_setprio(1);
#pragma unroll
      for (int kb = 0; kb < 2; ++kb) {
        const int o0 = (fr) * 128 + ((kb * 64 + fq * 16) ^ ((fr & 7) << 4));
        const int o1 = (16 + fr) * 128 + ((kb * 64 + fq * 16) ^ ((fr & 7) << 4));
        short8 pa0 = *(const short8*)((const char*)Ps[wid] + o0);
        short8 pa1 = *(const short8*)((const char*)Ps[wid] + o1);
#pragma unroll
        for (int f = 0; f < 8; ++f) {
          const int d = f * 16 + fr;
          const int p = (kb * 4 + fq) ^ (d & 7);
          short8 vf = *(const short8*)((const char*)Vts + d * 128 + p * 16);
          Oacc[0][f] = __builtin_amdgcn_mfma_f32_16x16x32_bf16(pa0, vf, Oacc[0][f], 0, 0, 0);
          Oacc[1][f] = __builtin_amdgcn_mfma_f32_16x16x32_bf16(pa1, vf, Oacc[1][f], 0, 0, 0);
        }
        Sacc[0] = __builtin_amdgcn_mfma_f32_16x16x32_bf16(pa0, ones, Sacc[0], 0, 0, 0);
        Sacc[1] = __builtin_amdgcn_mfma_f32_16x16x32_bf16(pa1, ones, Sacc[1], 0, 0, 0);
      }
      __builtin_amdgcn_s_setprio(0);
    }
    // K(t+1) landed (issued at iter start, covered by this tile's compute)
    wait_vmcnt<0>();
    __builtin_amdgcn_s_barrier();
  }

#pragma unroll
  for (int m = 0; m < 2; ++m)
#pragma unroll
    for (int j = 0; j < 4; ++j) {
      const float inv = 1.f / Sacc[m][j];
      const long r = q0 + wid * 32 + m * 16 + fq * 4 + j;
#pragma unroll
      for (int f = 0; f < 8; ++f)
        Ob[r * 4096 + h * 128 + f * 16 + fr] = f2b(Oacc[m][f][j] * inv);
    }
}

// ---------------- launch ----------------------------------------------------
extern "C" void kernel_launch(void* const* d_in, const int* in_sizes, int n_in,
                              void* d_out, int out_size, void* d_ws, size_t ws_size,
                              hipStream_t stream) {
  const float* hs   = (const float*)d_in[0];   // (2048, 4096)
  const float* cosb = (const float*)d_in[1];   // (2048, 128)
  const float* sinb = (const float*)d_in[2];   // (2048, 128)
  const float* wp   = (const float*)d_in[3];   // (12288, 4096)
  const float* wo   = (const float*)d_in[4];   // (4096, 4096)
  float* out = (float*)d_out;                  // (2048, 4096)
  char* ws = (char*)d_ws;

  // workspace (180 MB peak):
  //   [0,16M)    h_bf   -> reused by attn output after GEMM1
  //   [16M,116M) wp_bf  -> reused by wo_bf after GEMM1
  //   [116M,164M) qkv (q,k written; v region unused)
  //   [164M,180M) vt (4096 x 2048, written by GEMM1 epilogue)
  u16* h_bf  = (u16*)(ws);
  u16* attn  = (u16*)(ws);
  u16* wp_bf = (u16*)(ws + 16777216);
  u16* wo_bf = (u16*)(ws + 16777216);
  u16* qkv   = (u16*)(ws + 121634816);
  u16* vt    = (u16*)(ws + 171966464);

  cvt_hp<<<4096, 256, 0, stream>>>(hs, wp, h_bf, wp_bf);
  gemm8p<<<512, 512, 0, stream>>>(h_bf, wp_bf, qkv, vt, 2048, 12288, 4096);
  rope_qk<<<8192, 256, 0, stream>>>(qkv, cosb, sinb);
  attn_fwd<<<2560, 256, 0, stream>>>(qkv, qkv + 4096, vt, attn, wo, wo_bf);
  gemm2_128<<<512, 256, 0, stream>>>(attn, wo_bf, out, 2048, 4096, 4096);
}

// Round 20
// 407.127 us; speedup vs baseline: 1.0208x; 1.0208x over previous
//
#include <hip/hip_runtime.h>

typedef unsigned short u16;
typedef unsigned int   u32;
typedef __attribute__((ext_vector_type(8))) short short8;   // 8 x bf16
typedef __attribute__((ext_vector_type(4))) float f32x4;

__device__ __forceinline__ float b2f(u16 u) {
  union { float f; u32 i; } v; v.i = ((u32)u) << 16; return v.f;
}
__device__ __forceinline__ u16 f2b(float f) {
  union { float f; u32 i; } v; v.f = f;
  u32 r = v.i + 0x7fffu + ((v.i >> 16) & 1u);   // RNE
  return (u16)(r >> 16);
}

__device__ __forceinline__ void gload_lds16(const void* g, void* l) {
  __builtin_amdgcn_global_load_lds(
      (const __attribute__((address_space(1))) void*)g,
      (__attribute__((address_space(3))) void*)l, 16, 0, 0);
}

template <int N> __device__ __forceinline__ void wait_vmcnt() {
  if constexpr (N == 0)      asm volatile("s_waitcnt vmcnt(0)" ::: "memory");
  else if constexpr (N == 2) asm volatile("s_waitcnt vmcnt(2)" ::: "memory");
  else if constexpr (N == 3) asm volatile("s_waitcnt vmcnt(3)" ::: "memory");
  else if constexpr (N == 4) asm volatile("s_waitcnt vmcnt(4)" ::: "memory");
  else if constexpr (N == 6) asm volatile("s_waitcnt vmcnt(6)" ::: "memory");
  else static_assert(N < 0, "unsupported vmcnt literal");
}

// ---------------- f32 -> bf16 converts ----------------
__device__ __forceinline__ ushort4 cvt4(float4 v) {
  ushort4 o;
  o.x = f2b(v.x); o.y = f2b(v.y); o.z = f2b(v.z); o.w = f2b(v.w);
  return o;
}

__global__ __launch_bounds__(256) void cvt_hp(const float* __restrict__ hs,
                                              const float* __restrict__ wp,
                                              u16* __restrict__ h_bf,
                                              u16* __restrict__ wp_bf) {
  const long H4 = 2097152, W4 = 12582912;   // float4 counts
  for (long i = (long)blockIdx.x * 256 + threadIdx.x; i < H4 + W4;
       i += (long)gridDim.x * 256) {
    if (i < H4)
      ((ushort4*)h_bf)[i] = cvt4(((const float4*)hs)[i]);
    else
      ((ushort4*)wp_bf)[i - H4] = cvt4(((const float4*)wp)[i - H4]);
  }
}

__device__ __forceinline__ short8 frag_ld64(const u16* base, int rbase, int kk,
                                            int fr, int fq) {
  const int r = rbase + fr;
  return *(const short8*)(base + r * 64 + ((((kk << 2) + fq) ^ (r & 7)) << 3));
}

// ============ GEMM1: tile 256x192, minimal-barrier (R16/R18-exact) ==========
// Barrier audit: B frags are read ONLY in phase 1 -> lgkm(0)+barrier after
// ph1 makes B(t+2)->buf(t) staging safe. A(t+1)->buf^1 safe (reads retired
// in iter t-1 before its closing barrier). End-of-iter vmcnt(3)+barrier
// publishes tile t+1. 2 barriers/K-tile is the measured optimum (4: R15
// slower; 1: R19 slower).
__global__ __launch_bounds__(512, 2) void gemm8p(const u16* __restrict__ A,
                                                 const u16* __restrict__ B,
                                                 u16* __restrict__ Cq,
                                                 u16* __restrict__ VT,
                                                 int M, int N, int K) {
  constexpr int AE = 16384;                 // A region u16 (256x64)
  constexpr int BUFSZ = AE + 12288;         // + B region (192x64) = 28672 u16
  __shared__ u16 lds[2 * BUFSZ];            // 114,688 B
  const int tid = threadIdx.x;
  const int wid = tid >> 6, lane = tid & 63;
  const int fr = lane & 15, fq = lane >> 4;
  const int mA = (wid >> 2) * 128;          // wm in {0,1}
  const int nB = (wid & 3) * 48;            // wn in {0..3}

  const int nty = M >> 8;                   // 8
  const int qx = gridDim.x >> 3;
  const int wg = (blockIdx.x & 7) * qx + (blockIdx.x >> 3);
  const int by = wg % nty, bx = wg / nty;
  const long row0 = (long)by * 256, col0 = (long)bx * 192;

  const int rr8 = tid >> 3;
  const int jl = (tid & 7) ^ (rr8 & 7);
  const u16* gA = A + (row0 + rr8) * (long)K + jl * 8;
  const u16* gB = B + (col0 + rr8) * (long)K + jl * 8;

  f32x4 acc[8][3];
#pragma unroll
  for (int m = 0; m < 8; ++m)
#pragma unroll
    for (int n = 0; n < 3; ++n) acc[m][n] = f32x4{0.f, 0.f, 0.f, 0.f};

  const int NT = K >> 6;                    // BK = 64

  auto stageA = [&](int i, int t) {
    gload_lds16(gA + (long)(i * 64) * K + (long)t * 64,
                lds + (t & 1) * BUFSZ + (i * 512 + tid) * 8);
  };
  auto stageB = [&](int i, int t) {
    gload_lds16(gB + (long)(i * 64) * K + (long)t * 64,
                lds + (t & 1) * BUFSZ + AE + (i * 512 + tid) * 8);
  };

#pragma unroll
  for (int i = 0; i < 4; ++i) stageA(i, 0);
#pragma unroll
  for (int i = 0; i < 3; ++i) stageB(i, 0);
#pragma unroll
  for (int i = 0; i < 3; ++i) stageB(i, 1);
  wait_vmcnt<3>();
  __builtin_amdgcn_s_barrier();

  for (int t = 0; t < NT; ++t) {
    const u16* SA = lds + (t & 1) * BUFSZ;
    const u16* SB = SA + AE;
    short8 a0[4], a1[4], b0[3], b1[3];

    // ---- phase 1: (qm0,kk0); ALL B frags; stage A i=0,1; 12 MFMA ----
#pragma unroll
    for (int m = 0; m < 4; ++m) a0[m] = frag_ld64(SA, mA + m * 16, 0, fr, fq);
#pragma unroll
    for (int n = 0; n < 3; ++n) b0[n] = frag_ld64(SB, nB + n * 16, 0, fr, fq);
#pragma unroll
    for (int n = 0; n < 3; ++n) b1[n] = frag_ld64(SB, nB + n * 16, 1, fr, fq);
    if (t + 1 < NT) { stageA(0, t + 1); stageA(1, t + 1); }
    __builtin_amdgcn_s_setprio(1);
#pragma unroll
    for (int m = 0; m < 4; ++m)
#pragma unroll
      for (int n = 0; n < 3; ++n)
        acc[m][n] = __builtin_amdgcn_mfma_f32_16x16x32_bf16(a0[m], b0[n], acc[m][n], 0, 0, 0);
    __builtin_amdgcn_s_setprio(0);
    asm volatile("s_waitcnt lgkmcnt(0)" ::: "memory");   // all B(t) reads retired
    __builtin_amdgcn_s_barrier();                        // BARRIER 1 (B-region fence)

    // ---- phases 2-4 merged ----
#pragma unroll
    for (int m = 0; m < 4; ++m) a1[m] = frag_ld64(SA, mA + 64 + m * 16, 0, fr, fq);
    if (t + 1 < NT) { stageA(2, t + 1); stageA(3, t + 1); }
    __builtin_amdgcn_s_setprio(1);
#pragma unroll
    for (int m = 0; m < 4; ++m)
#pragma unroll
      for (int n = 0; n < 3; ++n)
        acc[4 + m][n] = __builtin_amdgcn_mfma_f32_16x16x32_bf16(a1[m], b0[n], acc[4 + m][n], 0, 0, 0);
    __builtin_amdgcn_s_setprio(0);

#pragma unroll
    for (int m = 0; m < 4; ++m) a0[m] = frag_ld64(SA, mA + m * 16, 1, fr, fq);
    if (t + 2 < NT) { stageB(0, t + 2); stageB(1, t + 2); }
    __builtin_amdgcn_s_setprio(1);
#pragma unroll
    for (int m = 0; m < 4; ++m)
#pragma unroll
      for (int n = 0; n < 3; ++n)
        acc[m][n] = __builtin_amdgcn_mfma_f32_16x16x32_bf16(a0[m], b1[n], acc[m][n], 0, 0, 0);
    __builtin_amdgcn_s_setprio(0);

#pragma unroll
    for (int m = 0; m < 4; ++m) a1[m] = frag_ld64(SA, mA + 64 + m * 16, 1, fr, fq);
    if (t + 2 < NT) stageB(2, t + 2);
    __builtin_amdgcn_s_setprio(1);
#pragma unroll
    for (int m = 0; m < 4; ++m)
#pragma unroll
      for (int n = 0; n < 3; ++n)
        acc[4 + m][n] = __builtin_amdgcn_mfma_f32_16x16x32_bf16(a1[m], b1[n], acc[4 + m][n], 0, 0, 0);
    __builtin_amdgcn_s_setprio(0);
    if (t + 2 < NT) wait_vmcnt<3>();
    else            wait_vmcnt<0>();
    __builtin_amdgcn_s_barrier();                        // BARRIER 2 (publish t+1)
  }

#pragma unroll
  for (int m = 0; m < 8; ++m)
#pragma unroll
    for (int n = 0; n < 3; ++n) {
      const long c = col0 + nB + n * 16 + fr;
      const long rb = row0 + mA + m * 16 + fq * 4;
      if (c >= 8192) {
        ushort4 o;
        o.x = f2b(acc[m][n][0]); o.y = f2b(acc[m][n][1]);
        o.z = f2b(acc[m][n][2]); o.w = f2b(acc[m][n][3]);
        *(ushort4*)(VT + (c - 8192) * 2048 + rb) = o;
      } else {
#pragma unroll
        for (int j = 0; j < 4; ++j) Cq[(rb + j) * N + c] = f2b(acc[m][n][j]);
      }
    }
}

// ============ GEMM2: tile 128x128, 2 blocks/CU, minimal-barrier (R18) =======
__global__ __launch_bounds__(256, 2) void gemm2_128(const u16* __restrict__ A,
                                                    const u16* __restrict__ B,
                                                    float* __restrict__ C,
                                                    int M, int N, int K) {
  constexpr int AE = 8192;                  // A region u16 (128x64)
  constexpr int BUFSZ = 2 * AE;             // + B region = 16384 u16
  __shared__ u16 lds[2 * BUFSZ];            // 65,536 B
  const int tid = threadIdx.x;
  const int wid = tid >> 6, lane = tid & 63;
  const int fr = lane & 15, fq = lane >> 4;
  const int mA = (wid >> 1) * 64;
  const int nB = (wid & 1) * 64;

  const int nty = M >> 7;                   // 16
  const int qx = gridDim.x >> 3;
  const int wg = (blockIdx.x & 7) * qx + (blockIdx.x >> 3);
  const int by = wg % nty, bx = wg / nty;
  const long row0 = (long)by * 128, col0 = (long)bx * 128;

  const int rr8 = tid >> 3;                 // 0..31
  const int jl = (tid & 7) ^ (rr8 & 7);
  const u16* gA = A + (row0 + rr8) * (long)K + jl * 8;
  const u16* gB = B + (col0 + rr8) * (long)K + jl * 8;

  f32x4 acc[4][4];
#pragma unroll
  for (int m = 0; m < 4; ++m)
#pragma unroll
    for (int n = 0; n < 4; ++n) acc[m][n] = f32x4{0.f, 0.f, 0.f, 0.f};

  const int NT = K >> 6;

  auto stageA = [&](int i, int t) {
    gload_lds16(gA + (long)(i * 32) * K + (long)t * 64,
                lds + (t & 1) * BUFSZ + (i * 256 + tid) * 8);
  };
  auto stageB = [&](int i, int t) {
    gload_lds16(gB + (long)(i * 32) * K + (long)t * 64,
                lds + (t & 1) * BUFSZ + AE + (i * 256 + tid) * 8);
  };

#pragma unroll
  for (int i = 0; i < 4; ++i) stageA(i, 0);
#pragma unroll
  for (int i = 0; i < 4; ++i) stageB(i, 0);
#pragma unroll
  for (int i = 0; i < 4; ++i) stageB(i, 1);
  wait_vmcnt<4>();
  __builtin_amdgcn_s_barrier();

  for (int t = 0; t < NT; ++t) {
    const u16* SA = lds + (t & 1) * BUFSZ;
    const u16* SB = SA + AE;
    short8 a[2], b0[4], b1[4];

    // ---- phase 1: a0-1 kk0 + ALL 8 B frags; stage A i=0,1; 8 MFMA ----
    a[0] = frag_ld64(SA, mA +  0, 0, fr, fq);
    a[1] = frag_ld64(SA, mA + 16, 0, fr, fq);
#pragma unroll
    for (int n = 0; n < 4; ++n) b0[n] = frag_ld64(SB, nB + n * 16, 0, fr, fq);
#pragma unroll
    for (int n = 0; n < 4; ++n) b1[n] = frag_ld64(SB, nB + n * 16, 1, fr, fq);
    if (t + 1 < NT) { stageA(0, t + 1); stageA(1, t + 1); }
    __builtin_amdgcn_s_setprio(1);
#pragma unroll
    for (int m = 0; m < 2; ++m)
#pragma unroll
      for (int n = 0; n < 4; ++n)
        acc[m][n] = __builtin_amdgcn_mfma_f32_16x16x32_bf16(a[m], b0[n], acc[m][n], 0, 0, 0);
    __builtin_amdgcn_s_setprio(0);
    asm volatile("s_waitcnt lgkmcnt(0)" ::: "memory");   // all B(t) reads retired
    __builtin_amdgcn_s_barrier();                        // BARRIER 1

    // ---- phases 2-4 merged ----
    a[0] = frag_ld64(SA, mA + 32, 0, fr, fq);
    a[1] = frag_ld64(SA, mA + 48, 0, fr, fq);
    if (t + 1 < NT) { stageA(2, t + 1); stageA(3, t + 1); }
    __builtin_amdgcn_s_setprio(1);
#pragma unroll
    for (int m = 0; m < 2; ++m)
#pragma unroll
      for (int n = 0; n < 4; ++n)
        acc[2 + m][n] = __builtin_amdgcn_mfma_f32_16x16x32_bf16(a[m], b0[n], acc[2 + m][n], 0, 0, 0);
    __builtin_amdgcn_s_setprio(0);

    a[0] = frag_ld64(SA, mA +  0, 1, fr, fq);
    a[1] = frag_ld64(SA, mA + 16, 1, fr, fq);
    if (t + 2 < NT) { stageB(0, t + 2); stageB(1, t + 2); }
    __builtin_amdgcn_s_setprio(1);
#pragma unroll
    for (int m = 0; m < 2; ++m)
#pragma unroll
      for (int n = 0; n < 4; ++n)
        acc[m][n] = __builtin_amdgcn_mfma_f32_16x16x32_bf16(a[m], b1[n], acc[m][n], 0, 0, 0);
    __builtin_amdgcn_s_setprio(0);

    a[0] = frag_ld64(SA, mA + 32, 1, fr, fq);
    a[1] = frag_ld64(SA, mA + 48, 1, fr, fq);
    if (t + 2 < NT) { stageB(2, t + 2); stageB(3, t + 2); }
    __builtin_amdgcn_s_setprio(1);
#pragma unroll
    for (int m = 0; m < 2; ++m)
#pragma unroll
      for (int n = 0; n < 4; ++n)
        acc[2 + m][n] = __builtin_amdgcn_mfma_f32_16x16x32_bf16(a[m], b1[n], acc[2 + m][n], 0, 0, 0);
    __builtin_amdgcn_s_setprio(0);
    if (t + 2 < NT) wait_vmcnt<4>();
    else            wait_vmcnt<0>();
    __builtin_amdgcn_s_barrier();                        // BARRIER 2
  }

#pragma unroll
  for (int m = 0; m < 4; ++m)
#pragma unroll
    for (int n = 0; n < 4; ++n)
#pragma unroll
      for (int j = 0; j < 4; ++j) {
        const long r = row0 + mA + m * 16 + fq * 4 + j;
        const long c = col0 + nB + n * 16 + fr;
        C[r * N + c] = acc[m][n][j];
      }
}

// -------- RoPE on q,k (rope-only, R18-exact) --------------------------------
__global__ __launch_bounds__(256) void rope_qk(u16* __restrict__ qkv,
                                               const float* __restrict__ cosb,
                                               const float* __restrict__ sinb) {
  const int idx = blockIdx.x * 256 + threadIdx.x;   // grid exact: 2,097,152
  const int dq  = idx & 15;
  const int h   = (idx >> 4) & 31;
  const int seg = (idx >> 9) & 1;                   // 0 = q, 1 = k
  const int s   = idx >> 10;
  const int d0  = dq * 4;
  u16* base = qkv + (long)s * 12288 + seg * 4096 + h * 128;
  const ushort4 x1 = *(const ushort4*)(base + d0);
  const ushort4 x2 = *(const ushort4*)(base + d0 + 64);
  const float4 c1 = *(const float4*)(cosb + s * 128 + d0);
  const float4 s1 = *(const float4*)(sinb + s * 128 + d0);
  const float4 c2 = *(const float4*)(cosb + s * 128 + d0 + 64);
  const float4 s2 = *(const float4*)(sinb + s * 128 + d0 + 64);
  const float scale = seg ? 1.0f : 0.08838834764831845f;   // 1/sqrt(128) on q
  float x1f[4] = {b2f(x1.x), b2f(x1.y), b2f(x1.z), b2f(x1.w)};
  float x2f[4] = {b2f(x2.x), b2f(x2.y), b2f(x2.z), b2f(x2.w)};
  const float c1a[4] = {c1.x, c1.y, c1.z, c1.w}, s1a[4] = {s1.x, s1.y, s1.z, s1.w};
  const float c2a[4] = {c2.x, c2.y, c2.z, c2.w}, s2a[4] = {s2.x, s2.y, s2.z, s2.w};
  ushort4 o1, o2;
  u16* o1p = (u16*)&o1; u16* o2p = (u16*)&o2;
#pragma unroll
  for (int j = 0; j < 4; ++j) {
    o1p[j] = f2b((x1f[j] * c1a[j] - x2f[j] * s1a[j]) * scale);
    o2p[j] = f2b((x2f[j] * c2a[j] + x1f[j] * s2a[j]) * scale);
  }
  *(ushort4*)(base + d0) = o1;
  *(ushort4*)(base + d0 + 64) = o2;
}

// ------- causal flash attention (R16-exact) + wo-convert tail-fill ----------
__global__ __launch_bounds__(256, 2) void attn_fwd(const u16* __restrict__ Qb,
                                                   const u16* __restrict__ Kb,
                                                   const u16* __restrict__ Vt,
                                                   u16* __restrict__ Ob,
                                                   const float* __restrict__ wo,
                                                   u16* __restrict__ wo_bf) {
  if (blockIdx.x >= 512) {                   // wo convert tail-fill
    const int n4 = 4194304;
    for (long i = (long)(blockIdx.x - 512) * 256 + threadIdx.x; i < n4;
         i += (long)2048 * 256)
      ((ushort4*)wo_bf)[i] = cvt4(((const float4*)wo)[i]);
    return;
  }
  const int bid = blockIdx.x;                // 0..511
  const int half = bid >> 8, ii = bid & 255;
  const int h = (ii >> 4) | (half << 4);     // 0..31
  const int qt = half ? 15 - (ii & 15) : (ii & 15);
  const int q0 = qt * 128;
  const int nt = 2 * qt + 2;
  const int tid = threadIdx.x;
  const int wid = tid >> 6, lane = tid & 63;
  const int fr = lane & 15, fq = lane >> 4;

  __shared__ u16 Ks[2][64 * 128];    // 2 x 16 KB (double-buffered)
  __shared__ u16 Vts[128 * 64];      // 16 KB (single)
  __shared__ u16 Ps[4][32 * 64];     // 16 KB, XOR-swizzled pitch 64

  short8 ones;
#pragma unroll
  for (int i = 0; i < 8; ++i) ones[i] = (short)0x3F80;   // bf16 1.0

  auto stageK = [&](int t, int buf) {
    const int kv0 = t * 64;
#pragma unroll
    for (int i = 0; i < 4; ++i) {
      const int c = wid * 4 + i;
      const int r = c * 4 + (lane >> 4);
      const int p = lane & 15;
      const int jsrc = p ^ (r & 7);
      gload_lds16(Kb + (long)(kv0 + r) * 12288 + h * 128 + jsrc * 8,
                  (char*)Ks[buf] + c * 1024);
    }
  };
  auto stageV = [&](int t) {
    const int kv0 = t * 64;
#pragma unroll
    for (int i = 0; i < 4; ++i) {
      const int c = wid * 4 + i;
      const int d = c * 8 + (lane >> 3);
      const int p = lane & 7;
      const int jsrc = p ^ (d & 7);
      gload_lds16(Vt + (long)(h * 128 + d) * 2048 + kv0 + jsrc * 8,
                  (char*)Vts + c * 1024);
    }
  };

  const int wq_hi = q0 + wid * 32 + 31;   // wave's max q row

  short8 qf[2][4];
#pragma unroll
  for (int m = 0; m < 2; ++m) {
    const long qrow = q0 + wid * 32 + m * 16 + fr;
#pragma unroll
    for (int kk = 0; kk < 4; ++kk)
      qf[m][kk] = *(const short8*)(Qb + qrow * 12288 + h * 128 + kk * 32 + fq * 8);
  }

  f32x4 Oacc[2][8], Sacc[2];
#pragma unroll
  for (int m = 0; m < 2; ++m) {
#pragma unroll
    for (int f = 0; f < 8; ++f) Oacc[m][f] = f32x4{0.f, 0.f, 0.f, 0.f};
    Sacc[m] = f32x4{0.f, 0.f, 0.f, 0.f};
  }
  float mrun[2];
  mrun[0] = -1e30f; mrun[1] = -1e30f;

  stageK(0, 0);
  wait_vmcnt<0>();
  __builtin_amdgcn_s_barrier();

  for (int t = 0; t < nt; ++t) {
    const int cur = t & 1;
    const int kv0 = t * 64;
    stageV(t);                               // V(t): 4 loads (issued first)
    if (t + 1 < nt) stageK(t + 1, cur ^ 1);  // K(t+1): 4 loads behind V

    const bool skip = kv0 > wq_hi;           // wave-uniform causal skip
    float P[2][4][4];
    if (!skip) {
      // swapped QK^T: lane = q-column (q=fr); reg j = kv=kv0+16n+4fq+j
      f32x4 S[2][4];
#pragma unroll
      for (int m = 0; m < 2; ++m)
#pragma unroll
        for (int n = 0; n < 4; ++n) S[m][n] = f32x4{0.f, 0.f, 0.f, 0.f};
      __builtin_amdgcn_s_setprio(1);
#pragma unroll
      for (int kk = 0; kk < 4; ++kk) {
        short8 kf[4];
#pragma unroll
        for (int n = 0; n < 4; ++n) {
          const int r = n * 16 + fr;
          const int p = (kk * 4 + fq) ^ (r & 7);
          kf[n] = *(const short8*)((const char*)Ks[cur] + r * 256 + p * 16);
        }
#pragma unroll
        for (int m = 0; m < 2; ++m)
#pragma unroll
          for (int n = 0; n < 4; ++n)
            S[m][n] = __builtin_amdgcn_mfma_f32_16x16x32_bf16(kf[n], qf[m][kk], S[m][n], 0, 0, 0);
      }
      __builtin_amdgcn_s_setprio(0);

#pragma unroll
      for (int m = 0; m < 2; ++m) {
        const int qi = q0 + wid * 32 + m * 16 + fr;   // lane's q column
        float tm = -1e30f;
#pragma unroll
        for (int n = 0; n < 4; ++n)
#pragma unroll
          for (int j = 0; j < 4; ++j) {
            const int kv = kv0 + n * 16 + fq * 4 + j;
            const float s = (kv <= qi) ? S[m][n][j] : -1e30f;
            P[m][n][j] = s;
            tm = fmaxf(tm, s);
          }
        tm = fmaxf(tm, __shfl_xor(tm, 16));
        tm = fmaxf(tm, __shfl_xor(tm, 32));
        // defer-max (T13): rescale only when max grew beyond THR=8
        if (__any(tm > mrun[m] + 8.f)) {
          const float mn = fmaxf(mrun[m], tm);
          const float al = __expf(mrun[m] - mn);
          mrun[m] = mn;
          float alr[4];
#pragma unroll
          for (int j = 0; j < 4; ++j) alr[j] = __shfl(al, fq * 4 + j);
#pragma unroll
          for (int f = 0; f < 8; ++f) {
            f32x4 o = Oacc[m][f];
#pragma unroll
            for (int j = 0; j < 4; ++j) o[j] *= alr[j];
            Oacc[m][f] = o;
          }
#pragma unroll
          for (int j = 0; j < 4; ++j) Sacc[m][j] *= alr[j];
        }
#pragma unroll
        for (int n = 0; n < 4; ++n)
#pragma unroll
          for (int j = 0; j < 4; ++j)
            P[m][n][j] = __expf(P[m][n][j] - mrun[m]);
      }

      // Ps write: row q=16m+fr, byte col (32n+8fq) ^ ((fr&7)<<4)
#pragma unroll
      for (int m = 0; m < 2; ++m)
#pragma unroll
        for (int n = 0; n < 4; ++n) {
          ushort4 w;
          u16* wp_ = (u16*)&w;
#pragma unroll
          for (int j = 0; j < 4; ++j) wp_[j] = f2b(P[m][n][j]);
          const int off = (m * 16 + fr) * 128 + ((n * 32 + fq * 8) ^ ((fr & 7) << 4));
          *(ushort4*)((char*)Ps[wid] + off) = w;
        }
    }

    // V(t) landed (4 oldest); K(t+1) stays in flight (counted, T4)
    if (t + 1 < nt) wait_vmcnt<4>();
    else            wait_vmcnt<0>();
    __builtin_amdgcn_s_barrier();

    if (!skip) {
      __builtin_amdgcn_s_setprio(1);
#pragma unroll
      for (int kb = 0; kb < 2; ++kb) {
        const int o0 = (fr) * 128 + ((kb * 64 + fq * 16) ^ ((fr & 7) << 4));
        const int o1 = (16 + fr) * 128 + ((kb * 64 + fq * 16) ^ ((fr & 7) << 4));
        short8 pa0 = *(const short8*)((const char*)Ps[wid] + o0);
        short8 pa1 = *(const short8*)((const char*)Ps[wid] + o1);
#pragma unroll
        for (int f = 0; f < 8; ++f) {
          const int d = f * 16 + fr;
          const int p = (kb * 4 + fq) ^ (d & 7);
          short8 vf = *(const short8*)((const char*)Vts + d * 128 + p * 16);
          Oacc[0][f] = __builtin_amdgcn_mfma_f32_16x16x32_bf16(pa0, vf, Oacc[0][f], 0, 0, 0);
          Oacc[1][f] = __builtin_amdgcn_mfma_f32_16x16x32_bf16(pa1, vf, Oacc[1][f], 0, 0, 0);
        }
        Sacc[0] = __builtin_amdgcn_mfma_f32_16x16x32_bf16(pa0, ones, Sacc[0], 0, 0, 0);
        Sacc[1] = __builtin_amdgcn_mfma_f32_16x16x32_bf16(pa1, ones, Sacc[1], 0, 0, 0);
      }
      __builtin_amdgcn_s_setprio(0);
    }
    // K(t+1) landed (issued at iter start, covered by this tile's compute)
    wait_vmcnt<0>();
    __builtin_amdgcn_s_barrier();
  }

#pragma unroll
  for (int m = 0; m < 2; ++m)
#pragma unroll
    for (int j = 0; j < 4; ++j) {
      const float inv = 1.f / Sacc[m][j];
      const long r = q0 + wid * 32 + m * 16 + fq * 4 + j;
#pragma unroll
      for (int f = 0; f < 8; ++f)
        Ob[r * 4096 + h * 128 + f * 16 + fr] = f2b(Oacc[m][f][j] * inv);
    }
}

// ---------------- launch ----------------------------------------------------
extern "C" void kernel_launch(void* const* d_in, const int* in_sizes, int n_in,
                              void* d_out, int out_size, void* d_ws, size_t ws_size,
                              hipStream_t stream) {
  const float* hs   = (const float*)d_in[0];   // (2048, 4096)
  const float* cosb = (const float*)d_in[1];   // (2048, 128)
  const float* sinb = (const float*)d_in[2];   // (2048, 128)
  const float* wp   = (const float*)d_in[3];   // (12288, 4096)
  const float* wo   = (const float*)d_in[4];   // (4096, 4096)
  float* out = (float*)d_out;                  // (2048, 4096)
  char* ws = (char*)d_ws;

  // workspace (180 MB peak):
  //   [0,16M)    h_bf   -> reused by attn output after GEMM1
  //   [16M,116M) wp_bf  -> reused by wo_bf after GEMM1
  //   [116M,164M) qkv (q,k written; v region unused)
  //   [164M,180M) vt (4096 x 2048, written by GEMM1 epilogue)
  u16* h_bf  = (u16*)(ws);
  u16* attn  = (u16*)(ws);
  u16* wp_bf = (u16*)(ws + 16777216);
  u16* wo_bf = (u16*)(ws + 16777216);
  u16* qkv   = (u16*)(ws + 121634816);
  u16* vt    = (u16*)(ws + 171966464);

  cvt_hp<<<4096, 256, 0, stream>>>(hs, wp, h_bf, wp_bf);
  gemm8p<<<512, 512, 0, stream>>>(h_bf, wp_bf, qkv, vt, 2048, 12288, 4096);
  rope_qk<<<8192, 256, 0, stream>>>(qkv, cosb, sinb);
  attn_fwd<<<2560, 256, 0, stream>>>(qkv, qkv + 4096, vt, attn, wo, wo_bf);
  gemm2_128<<<512, 256, 0, stream>>>(attn, wo_bf, out, 2048, 4096, 4096);
}